// Round 1
// baseline (410.831 us; speedup 1.0000x reference)
//
#include <hip/hip_runtime.h>
#include <hip/hip_bf16.h>

// Fused "RNN" (actually parallel over T since h0 never updates):
//   hd = W_hh @ h0 + b_ih + b_hh                       (tiny kernel -> d_ws)
//   out[t] = relu(x[t] @ W_ih^T + hd) @ W_out + b_out   (fused MFMA kernel)
//
// GEMM1 computed transposed: h^T = W_ih * x^T  (D rows = neurons, cols = time)
//   -> C layout gives each lane 4 CONSECUTIVE neurons => ds_write_b64 to LDS.
// GEMM2 computed transposed: out^T = W_out^T * h^T
//   -> B-frag of h is contiguous ds_read_b128; D stores as global_store_dwordx4.
// No __syncthreads anywhere: each wave owns its private LDS region.

typedef __attribute__((ext_vector_type(8))) short short8v;
typedef __attribute__((ext_vector_type(4))) short short4v;
typedef __attribute__((ext_vector_type(4))) float f32x4;

static __device__ __forceinline__ short f2bs(float f) {
    union { __hip_bfloat16 b; short s; } u;
    u.b = __float2bfloat16(f);   // RNE rounding
    return u.s;
}

static __device__ __forceinline__ short8v pack8(f32x4 a, f32x4 b) {
    short8v r;
    r[0] = f2bs(a[0]); r[1] = f2bs(a[1]); r[2] = f2bs(a[2]); r[3] = f2bs(a[3]);
    r[4] = f2bs(b[0]); r[5] = f2bs(b[1]); r[6] = f2bs(b[2]); r[7] = f2bs(b[3]);
    return r;
}

// hd[n] = b_ih[n] + b_hh[n] + sum_k W_hh[n][k] * h0[k]
__global__ void hd_kernel(const float* __restrict__ Whh, const float* __restrict__ bih,
                          const float* __restrict__ bhh, const float* __restrict__ h0,
                          float* __restrict__ hd) {
    int n = threadIdx.x;
    if (n < 128) {
        float s = bih[n] + bhh[n];
        for (int k = 0; k < 128; ++k) s += Whh[n * 128 + k] * h0[k];
        hd[n] = s;
    }
}

// LDS h-tile stride: 136 bf16 elems (=272 B) -> b64 writes 8B-aligned, b128 reads 16B-aligned.
#define HSTRIDE 136

__global__ __launch_bounds__(256, 2)
void rnn_fused(const float* __restrict__ x, const float* __restrict__ Wih,
               const float* __restrict__ Wout, const float* __restrict__ bout,
               const float* __restrict__ hd, float* __restrict__ out, int T) {
    const int lane = threadIdx.x & 63;
    const int wave = threadIdx.x >> 6;
    const int c    = lane & 15;   // time index within tile (D col / A,B row idx)
    const int q    = lane >> 4;   // quad
    const int nwaves = gridDim.x * 4;
    const int gw     = blockIdx.x * 4 + wave;
    const int NT     = T >> 4;    // T is a multiple of 16 (T = 1048576)

    __shared__ __align__(16) short hbuf[4 * 16 * HSTRIDE];
    short* hrow = &hbuf[wave * (16 * HSTRIDE)];

    // ---- preload W_ih A-frags: A[m=neuron][k=input]; lane holds row mt*16+c, k = kc*32+q*8+j
    short8v a_w[8][2];
#pragma unroll
    for (int mt = 0; mt < 8; ++mt) {
#pragma unroll
        for (int kc = 0; kc < 2; ++kc) {
            const float* p = Wih + (mt * 16 + c) * 64 + kc * 32 + q * 8;
            f32x4 f0 = *(const f32x4*)p;
            f32x4 f1 = *(const f32x4*)(p + 4);
            a_w[mt][kc] = pack8(f0, f1);
        }
    }

    // ---- preload W_out^T A-frags: A[m=o][k=neuron] = Wout[k][o]; o = mt*16+c, k = kc*32+q*8+j
    short8v a_o[2][4];
#pragma unroll
    for (int mt = 0; mt < 2; ++mt) {
#pragma unroll
        for (int kc = 0; kc < 4; ++kc) {
            short8v v;
#pragma unroll
            for (int j = 0; j < 8; ++j)
                v[j] = f2bs(Wout[(kc * 32 + q * 8 + j) * 32 + mt * 16 + c]);
            a_o[mt][kc] = v;
        }
    }

    // ---- hidden drive per lane: hd[mt*16 + q*4 + r] seeds GEMM1 acc (C/D row = neuron)
    f32x4 hd4[8];
#pragma unroll
    for (int mt = 0; mt < 8; ++mt) hd4[mt] = *(const f32x4*)(hd + mt * 16 + q * 4);
    // ---- b_out per lane: bout[mt*16 + q*4 + r] seeds GEMM2 acc (C/D row = output)
    f32x4 bo4[2];
#pragma unroll
    for (int mt = 0; mt < 2; ++mt) bo4[mt] = *(const f32x4*)(bout + mt * 16 + q * 4);

    // ---- x prefetch registers (B-frag of x^T: lane holds x[t0+c][kc*32+q*8+j])
    f32x4 xa, xb, xc2, xd;
    int tile = gw;
    if (tile < NT) {
        const f32x4* xp = (const f32x4*)(x + ((size_t)(tile * 16 + c)) * 64 + q * 8);
        xa = xp[0]; xb = xp[1]; xc2 = xp[8]; xd = xp[9];
    }

    while (tile < NT) {
        f32x4 c0 = xa, c1 = xb, c2 = xc2, c3 = xd;
        const int nxt = tile + nwaves;
        if (nxt < NT) {  // prefetch next tile (wave-uniform branch)
            const f32x4* xp = (const f32x4*)(x + ((size_t)(nxt * 16 + c)) * 64 + q * 8);
            xa = xp[0]; xb = xp[1]; xc2 = xp[8]; xd = xp[9];
        }

        short8v xb0 = pack8(c0, c1);   // k = 0..31
        short8v xb1 = pack8(c2, c3);   // k = 32..63

        // GEMM1: h^T tile [128 neurons x 16 times], acc seeded with hidden drive
        f32x4 acc[8];
#pragma unroll
        for (int mt = 0; mt < 8; ++mt) {
            acc[mt] = __builtin_amdgcn_mfma_f32_16x16x32_bf16(a_w[mt][0], xb0, hd4[mt], 0, 0, 0);
            acc[mt] = __builtin_amdgcn_mfma_f32_16x16x32_bf16(a_w[mt][1], xb1, acc[mt], 0, 0, 0);
        }

        // ReLU -> bf16 -> LDS [time][neuron]; lane writes 4 consecutive neurons (b64)
#pragma unroll
        for (int mt = 0; mt < 8; ++mt) {
            short4v s;
            s[0] = f2bs(fmaxf(acc[mt][0], 0.f));
            s[1] = f2bs(fmaxf(acc[mt][1], 0.f));
            s[2] = f2bs(fmaxf(acc[mt][2], 0.f));
            s[3] = f2bs(fmaxf(acc[mt][3], 0.f));
            *(short4v*)&hrow[c * HSTRIDE + mt * 16 + q * 4] = s;
        }

        // B-frags of h^T: lane reads h[c][kc*32+q*8 .. +7] contiguous (b128)
        short8v hb0 = *(const short8v*)&hrow[c * HSTRIDE + 0 * 32 + q * 8];
        short8v hb1 = *(const short8v*)&hrow[c * HSTRIDE + 1 * 32 + q * 8];
        short8v hb2 = *(const short8v*)&hrow[c * HSTRIDE + 2 * 32 + q * 8];
        short8v hb3 = *(const short8v*)&hrow[c * HSTRIDE + 3 * 32 + q * 8];

        // GEMM2: out^T = W_out^T * h^T, acc seeded with b_out
        f32x4 o0 = bo4[0], o1 = bo4[1];
        o0 = __builtin_amdgcn_mfma_f32_16x16x32_bf16(a_o[0][0], hb0, o0, 0, 0, 0);
        o1 = __builtin_amdgcn_mfma_f32_16x16x32_bf16(a_o[1][0], hb0, o1, 0, 0, 0);
        o0 = __builtin_amdgcn_mfma_f32_16x16x32_bf16(a_o[0][1], hb1, o0, 0, 0, 0);
        o1 = __builtin_amdgcn_mfma_f32_16x16x32_bf16(a_o[1][1], hb1, o1, 0, 0, 0);
        o0 = __builtin_amdgcn_mfma_f32_16x16x32_bf16(a_o[0][2], hb2, o0, 0, 0, 0);
        o1 = __builtin_amdgcn_mfma_f32_16x16x32_bf16(a_o[1][2], hb2, o1, 0, 0, 0);
        o0 = __builtin_amdgcn_mfma_f32_16x16x32_bf16(a_o[0][3], hb3, o0, 0, 0, 0);
        o1 = __builtin_amdgcn_mfma_f32_16x16x32_bf16(a_o[1][3], hb3, o1, 0, 0, 0);

        // D2[row = out_idx = mt*16+q*4+r][col = time = c] -> out[t0+c][mt*16+q*4 .. +3]
        float* op = out + ((size_t)(tile * 16 + c)) * 32 + q * 4;
        *(f32x4*)(op)      = o0;
        *(f32x4*)(op + 16) = o1;

        tile = nxt;
    }
}

extern "C" void kernel_launch(void* const* d_in, const int* in_sizes, int n_in,
                              void* d_out, int out_size, void* d_ws, size_t ws_size,
                              hipStream_t stream) {
    const float* x    = (const float*)d_in[0];
    const float* Wih  = (const float*)d_in[1];
    const float* Whh  = (const float*)d_in[2];
    const float* bih  = (const float*)d_in[3];
    const float* bhh  = (const float*)d_in[4];
    const float* Wout = (const float*)d_in[5];
    const float* bout = (const float*)d_in[6];
    const float* h0   = (const float*)d_in[7];
    float* out = (float*)d_out;
    float* hd  = (float*)d_ws;   // 128 floats of scratch

    const int T = in_sizes[0] / 64;   // 1048576

    hd_kernel<<<1, 128, 0, stream>>>(Whh, bih, bhh, h0, hd);
    rnn_fused<<<512, 256, 0, stream>>>(x, Wih, Wout, bout, hd, out, T);
}